// Round 2
// baseline (95.410 us; speedup 1.0000x reference)
//
#include <hip/hip_runtime.h>
#include <stdint.h>

typedef __attribute__((ext_vector_type(8))) short short8;
typedef __attribute__((ext_vector_type(4))) float f32x4;

#define N_ROWS 4096
#define D_DIM  256
#define NT     8192
#define TILE   128
#define NTILE  64            // 8192 / 128
#define NBLK   (NTILE * (NTILE + 1) / 2)   // 2080 lower-triangular tiles

__device__ __forceinline__ unsigned short f2bf(float f) {
  unsigned int u = __float_as_uint(f);
  u += 0x7fffu + ((u >> 16) & 1u);          // round-to-nearest-even
  return (unsigned short)(u >> 16);
}

// ---------------- prep: f32 -> bf16 + exact f32 row norms ----------------
__global__ __launch_bounds__(256) void mmd_prep(
    const float* __restrict__ x1, const float* __restrict__ x2,
    unsigned short* __restrict__ Zb, float* __restrict__ norms) {
  const int t = threadIdx.x, w = t >> 6, l = t & 63;
  const int r = blockIdx.x * 4 + w;                      // one wave per row
  const float* src = (r < N_ROWS) ? (x1 + (size_t)r * D_DIM)
                                  : (x2 + (size_t)(r - N_ROWS) * D_DIM);
  const float4 v = *(const float4*)(src + l * 4);
  float sq = v.x * v.x + v.y * v.y + v.z * v.z + v.w * v.w;
#pragma unroll
  for (int off = 32; off > 0; off >>= 1) sq += __shfl_down(sq, off);
  if (l == 0) norms[r] = sq;
  ushort4 o;
  o.x = f2bf(v.x); o.y = f2bf(v.y); o.z = f2bf(v.z); o.w = f2bf(v.w);
  *(ushort4*)(Zb + (size_t)r * D_DIM + l * 4) = o;
}

// ------------- main: triangular tiles of G = Z Z^T, fragments direct from L2 -
__global__ __launch_bounds__(256) void mmd_main(
    const unsigned short* __restrict__ Zb,
    const float* __restrict__ norms,
    float* __restrict__ partials) {
  // decode linear triangular index -> (br, bc), bc <= br
  const int p = blockIdx.x;
  int br = (int)((sqrtf(8.0f * (float)p + 1.0f) - 1.0f) * 0.5f);
  while ((br + 1) * (br + 2) / 2 <= p) ++br;   // fixup float error
  while (br * (br + 1) / 2 > p) --br;
  const int bc = p - br * (br + 1) / 2;

  const int t = threadIdx.x;
  const int w = t >> 6, l = t & 63;
  const int wr = (w >> 1) * 64, wc = (w & 1) * 64;   // wave -> 64x64 sub-tile
  const int fr = l & 15, fq = l >> 4;

  // per-lane fragment base pointers (row-major Z, 256 bf16 per row)
  const unsigned short* pa[4];
  const unsigned short* pb[4];
#pragma unroll
  for (int m = 0; m < 4; ++m)
    pa[m] = Zb + (size_t)(br * TILE + wr + m * 16 + fr) * D_DIM + fq * 8;
#pragma unroll
  for (int n = 0; n < 4; ++n)
    pb[n] = Zb + (size_t)(bc * TILE + wc + n * 16 + fr) * D_DIM + fq * 8;

  f32x4 acc[4][4];
#pragma unroll
  for (int m = 0; m < 4; ++m)
#pragma unroll
    for (int n = 0; n < 4; ++n)
      acc[m][n] = (f32x4){0.0f, 0.0f, 0.0f, 0.0f};

  short8 aP[4], bP[4], aQ[4], bQ[4];

#define LOADK(A, B, K)                                            \
  do {                                                            \
    _Pragma("unroll") for (int m = 0; m < 4; ++m)                 \
        (A)[m] = *(const short8*)(pa[m] + (K) * 32);              \
    _Pragma("unroll") for (int n = 0; n < 4; ++n)                 \
        (B)[n] = *(const short8*)(pb[n] + (K) * 32);              \
  } while (0)

#define MFMAK(A, B)                                               \
  do {                                                            \
    _Pragma("unroll") for (int m = 0; m < 4; ++m)                 \
        _Pragma("unroll") for (int n = 0; n < 4; ++n)             \
            acc[m][n] = __builtin_amdgcn_mfma_f32_16x16x32_bf16(  \
                (A)[m], (B)[n], acc[m][n], 0, 0, 0);              \
  } while (0)

  // 8 K-steps of 32, 2-deep register ping-pong, no barriers
  LOADK(aP, bP, 0);
  LOADK(aQ, bQ, 1);
  MFMAK(aP, bP);
  LOADK(aP, bP, 2);
  MFMAK(aQ, bQ);
  LOADK(aQ, bQ, 3);
  MFMAK(aP, bP);
  LOADK(aP, bP, 4);
  MFMAK(aQ, bQ);
  LOADK(aQ, bQ, 5);
  MFMAK(aP, bP);
  LOADK(aP, bP, 6);
  MFMAK(aQ, bQ);
  LOADK(aQ, bQ, 7);
  MFMAK(aP, bP);
  MFMAK(aQ, bQ);

  // epilogue: d = |xi|^2 + |xj|^2 - 2 dot; sum_g exp(-c_g d),
  // c = 0.02 * {1,4,16,100,400} -> powers of one exp.
  float nr[16];
#pragma unroll
  for (int m = 0; m < 4; ++m)
#pragma unroll
    for (int r = 0; r < 4; ++r)
      nr[m * 4 + r] = norms[br * TILE + wr + m * 16 + fq * 4 + r];
  float nc[4];
#pragma unroll
  for (int n = 0; n < 4; ++n)
    nc[n] = norms[bc * TILE + wc + n * 16 + fr];

  float factor = ((br < 32) == (bc < 32)) ? 1.0f : -1.0f;  // same side vs cross
  if (br != bc) factor *= 2.0f;                            // off-diag tile: x2
  const bool diag = (br == bc);

  float sum = 0.0f;
#pragma unroll
  for (int m = 0; m < 4; ++m) {
#pragma unroll
    for (int n = 0; n < 4; ++n) {
#pragma unroll
      for (int r = 0; r < 4; ++r) {
        const int i = wr + m * 16 + fq * 4 + r;   // C layout: row=(l>>4)*4+reg
        const int j = wc + n * 16 + fr;           //           col=l&15
        float d = nr[m * 4 + r] + nc[n] - 2.0f * acc[m][n][r];
        d = fmaxf(d, 0.0f);
        const float u = __expf(-0.02f * d);
        const float u2 = u * u, u4 = u2 * u2;
        const float u8 = u4 * u4, u16 = u8 * u8;
        const float u32v = u16 * u16, u64v = u32v * u32v;
        const float u100 = u64v * u32v * u4;
        const float u200 = u100 * u100, u400 = u200 * u200;
        float S = u + u4 + u16 + u100 + u400;
        if (diag && i == j) S = 0.0f;             // diagonal added analytically
        sum += S;
      }
    }
  }
  sum *= factor;

  __shared__ float red[256];
  red[t] = sum;
  __syncthreads();
#pragma unroll
  for (int k = 128; k > 0; k >>= 1) {
    if (t < k) red[t] += red[t + k];
    __syncthreads();
  }
  if (t == 0) partials[p] = red[0];
}

// ---------------- finish: deterministic sum + diagonal constant + sqrt -------
__global__ __launch_bounds__(256) void mmd_finish(
    const float* __restrict__ partials, float* __restrict__ out) {
  __shared__ float red[256];
  const int t = threadIdx.x;
  float s = 0.0f;
  for (int i = t; i < NBLK; i += 256) s += partials[i];
  red[t] = s;
  __syncthreads();
#pragma unroll
  for (int k = 128; k > 0; k >>= 1) {
    if (t < k) red[t] += red[t + k];
    __syncthreads();
  }
  if (t == 0) {
    const float total = red[0] + 40960.0f;   // 2*4096 diag elems * 5 gammas
    out[0] = sqrtf(fmaxf(total, 0.0f) / 83886080.0f);  // / (5 * 4096^2)
  }
}

extern "C" void kernel_launch(void* const* d_in, const int* in_sizes, int n_in,
                              void* d_out, int out_size, void* d_ws, size_t ws_size,
                              hipStream_t stream) {
  const float* x1 = (const float*)d_in[0];
  const float* x2 = (const float*)d_in[1];
  unsigned short* Zb = (unsigned short*)d_ws;                       // 4 MiB bf16 Z
  float* norms = (float*)((char*)d_ws + (size_t)NT * D_DIM * 2);    // 32 KiB
  float* partials = norms + NT;                                     // 8.1 KiB
  float* out = (float*)d_out;

  mmd_prep<<<dim3(NT / 4), dim3(256), 0, stream>>>(x1, x2, Zb, norms);
  mmd_main<<<dim3(NBLK), dim3(256), 0, stream>>>(Zb, norms, partials);
  mmd_finish<<<dim3(1), dim3(256), 0, stream>>>(partials, out);
}

// Round 3
// 94.081 us; speedup vs baseline: 1.0141x; 1.0141x over previous
//
#include <hip/hip_runtime.h>
#include <stdint.h>

typedef __attribute__((ext_vector_type(8))) short short8;
typedef __attribute__((ext_vector_type(4))) float f32x4;

#define N_ROWS 4096
#define D_DIM  256
#define NT     8192
#define TILE   128
#define BK     64
#define NTILE  64                           // 8192 / 128
#define NBLK   (NTILE * (NTILE + 1) / 2)    // 2080 lower-triangular tiles

__device__ __forceinline__ unsigned short f2bf(float f) {
  unsigned int u = __float_as_uint(f);
  u += 0x7fffu + ((u >> 16) & 1u);          // round-to-nearest-even
  return (unsigned short)(u >> 16);
}

__device__ __forceinline__ void gload_lds16(const void* g, void* l) {
  __builtin_amdgcn_global_load_lds(
      (const __attribute__((address_space(1))) unsigned int*)g,
      (__attribute__((address_space(3))) unsigned int*)l, 16, 0, 0);
}

// ---------------- prep: f32 -> bf16 + exact f32 row norms + counter zero ----
__global__ __launch_bounds__(256) void mmd_prep(
    const float* __restrict__ x1, const float* __restrict__ x2,
    unsigned short* __restrict__ Zb, float* __restrict__ norms,
    unsigned int* __restrict__ counter) {
  if (blockIdx.x == 0 && threadIdx.x == 0) *counter = 0u;
  const int t = threadIdx.x, w = t >> 6, l = t & 63;
  const int r = blockIdx.x * 4 + w;                      // one wave per row
  const float* src = (r < N_ROWS) ? (x1 + (size_t)r * D_DIM)
                                  : (x2 + (size_t)(r - N_ROWS) * D_DIM);
  const float4 v = *(const float4*)(src + l * 4);
  float sq = v.x * v.x + v.y * v.y + v.z * v.z + v.w * v.w;
#pragma unroll
  for (int off = 32; off > 0; off >>= 1) sq += __shfl_down(sq, off);
  if (l == 0) norms[r] = sq;
  ushort4 o;
  o.x = f2bf(v.x); o.y = f2bf(v.y); o.z = f2bf(v.z); o.w = f2bf(v.w);
  *(ushort4*)(Zb + (size_t)r * D_DIM + l * 4) = o;
}

// ------- main: triangular tiles of G = Z Z^T, 2-phase LDS pipeline + fused exp
__global__ __launch_bounds__(256, 2) void mmd_main(
    const unsigned short* __restrict__ Zb,
    const float* __restrict__ norms,
    float* partials, unsigned int* counter, float* out) {
  __shared__ __align__(16) unsigned short As[2][TILE * BK];   // 2 x 16 KB
  __shared__ __align__(16) unsigned short Bs[2][TILE * BK];   // 2 x 16 KB
  __shared__ float red[256];
  __shared__ int amLastSh;

  // decode linear triangular index -> (br, bc), bc <= br
  const int p = blockIdx.x;
  int br = (int)((sqrtf(8.0f * (float)p + 1.0f) - 1.0f) * 0.5f);
  while ((br + 1) * (br + 2) / 2 <= p) ++br;
  while (br * (br + 1) / 2 > p) --br;
  const int bc = p - br * (br + 1) / 2;

  const int t = threadIdx.x;
  const int w = t >> 6, l = t & 63;
  const int wr = (w >> 1) * 64, wc = (w & 1) * 64;   // wave -> 64x64 sub-tile
  const int fr = l & 15, fq = l >> 4;

  const int aRow0 = br * TILE, bRow0 = bc * TILE;

  // staging geometry: per round q, wave w writes LDS rows q*32+w*8 .. +8
  // linearly (HW: uniform base + lane*16). phys row r = q*32+w*8+(l>>3),
  // phys chunk cp = l&7. We pre-swizzle the GLOBAL source so phys chunk cp
  // holds logical chunk cl = cp ^ (r&7)  (rule #21: swizzle source + read).
  const int srow = w * 8 + (l >> 3);
  const int clA = (l & 7) ^ (srow & 7);     // q*32 is 0 mod 8 -> q-independent

#define STAGE(buf, kt)                                                       \
  do {                                                                       \
    _Pragma("unroll") for (int q = 0; q < 4; ++q) {                          \
      const unsigned short* ga = Zb +                                        \
          (size_t)(aRow0 + q * 32 + srow) * D_DIM + (kt) * BK + clA * 8;     \
      gload_lds16(ga, (char*)&As[buf][0] + q * 4096 + w * 1024);             \
      const unsigned short* gb = Zb +                                        \
          (size_t)(bRow0 + q * 32 + srow) * D_DIM + (kt) * BK + clA * 8;     \
      gload_lds16(gb, (char*)&Bs[buf][0] + q * 4096 + w * 1024);             \
    }                                                                        \
  } while (0)

  f32x4 acc[4][4];
#pragma unroll
  for (int m = 0; m < 4; ++m)
#pragma unroll
    for (int n = 0; n < 4; ++n)
      acc[m][n] = (f32x4){0.0f, 0.0f, 0.0f, 0.0f};

  // hoist norm loads above the K-loop (L2 latency hides under pipeline)
  float nr[16];
#pragma unroll
  for (int m = 0; m < 4; ++m)
#pragma unroll
    for (int r = 0; r < 4; ++r)
      nr[m * 4 + r] = norms[aRow0 + wr + m * 16 + fq * 4 + r];
  float nc[4];
#pragma unroll
  for (int n = 0; n < 4; ++n)
    nc[n] = norms[bRow0 + wc + n * 16 + fr];

#define COMPUTE(buf)                                                         \
  do {                                                                       \
    short8 a[4][2], b[4][2];                                                 \
    _Pragma("unroll") for (int m = 0; m < 4; ++m) {                          \
      const int row = wr + m * 16 + fr;                                      \
      _Pragma("unroll") for (int kk = 0; kk < 2; ++kk) {                     \
        const int cl2 = kk * 4 + fq;                                         \
        a[m][kk] = *(const short8*)(                                         \
            &As[buf][row * BK + ((cl2 ^ (row & 7)) << 3)]);                  \
      }                                                                      \
    }                                                                        \
    _Pragma("unroll") for (int n = 0; n < 4; ++n) {                          \
      const int row = wc + n * 16 + fr;                                      \
      _Pragma("unroll") for (int kk = 0; kk < 2; ++kk) {                     \
        const int cl2 = kk * 4 + fq;                                         \
        b[n][kk] = *(const short8*)(                                         \
            &Bs[buf][row * BK + ((cl2 ^ (row & 7)) << 3)]);                  \
      }                                                                      \
    }                                                                        \
    _Pragma("unroll") for (int kk = 0; kk < 2; ++kk)                         \
      _Pragma("unroll") for (int m = 0; m < 4; ++m)                          \
        _Pragma("unroll") for (int n = 0; n < 4; ++n)                        \
          acc[m][n] = __builtin_amdgcn_mfma_f32_16x16x32_bf16(               \
              a[m][kk], b[n][kk], acc[m][n], 0, 0, 0);                       \
  } while (0)

  // 2-phase pipeline: stage(t+1) issued BEFORE compute(t); 1 barrier / K-tile
  STAGE(0, 0);
  __syncthreads();                     // drain prologue stage
#pragma unroll
  for (int kt = 0; kt < 3; ++kt) {
    STAGE((kt + 1) & 1, kt + 1);       // prefetch next K-tile
    COMPUTE(kt & 1);
    __syncthreads();                   // vmcnt(0)+lgkmcnt(0)+barrier
  }
  COMPUTE(1);                          // last K-tile, no prefetch

  // epilogue: d = |xi|^2 + |xj|^2 - 2 dot; sum_g exp(-c_g d),
  // c = 0.02 * {1,4,16,100,400} -> powers of one exp.
  float factor = ((br < 32) == (bc < 32)) ? 1.0f : -1.0f;  // same side vs cross
  if (br != bc) factor *= 2.0f;                            // off-diag tile: x2
  const bool diag = (br == bc);

  float sum = 0.0f;
#pragma unroll
  for (int m = 0; m < 4; ++m) {
#pragma unroll
    for (int n = 0; n < 4; ++n) {
#pragma unroll
      for (int r = 0; r < 4; ++r) {
        const int i = wr + m * 16 + fq * 4 + r;   // C layout: row=(l>>4)*4+reg
        const int j = wc + n * 16 + fr;           //           col=l&15
        float d = nr[m * 4 + r] + nc[n] - 2.0f * acc[m][n][r];
        d = fmaxf(d, 0.0f);
        const float u = __expf(-0.02f * d);
        const float u2 = u * u, u4 = u2 * u2;
        const float u8 = u4 * u4, u16 = u8 * u8;
        const float u32v = u16 * u16, u64v = u32v * u32v;
        const float u100 = u64v * u32v * u4;
        const float u200 = u100 * u100, u400 = u200 * u200;
        float S = u + u4 + u16 + u100 + u400;
        if (diag && i == j) S = 0.0f;             // diagonal added analytically
        sum += S;
      }
    }
  }
  sum *= factor;

  red[t] = sum;
  __syncthreads();
#pragma unroll
  for (int k = 128; k > 0; k >>= 1) {
    if (t < k) red[t] += red[t + k];
    __syncthreads();
  }

  // ---- fused finish: last block to arrive reduces all partials ----
  if (t == 0) {
    __hip_atomic_store(&partials[p], red[0], __ATOMIC_RELEASE,
                       __HIP_MEMORY_SCOPE_AGENT);
    unsigned int old = __hip_atomic_fetch_add(counter, 1u, __ATOMIC_ACQ_REL,
                                              __HIP_MEMORY_SCOPE_AGENT);
    amLastSh = (old == NBLK - 1) ? 1 : 0;
  }
  __syncthreads();
  if (amLastSh) {
    float s = 0.0f;
    for (int i = t; i < NBLK; i += 256)
      s += __hip_atomic_load(&partials[i], __ATOMIC_RELAXED,
                             __HIP_MEMORY_SCOPE_AGENT);
    red[t] = s;
    __syncthreads();
#pragma unroll
    for (int k = 128; k > 0; k >>= 1) {
      if (t < k) red[t] += red[t + k];
      __syncthreads();
    }
    if (t == 0) {
      const float total = red[0] + 40960.0f;  // 2*4096 diag elems * 5 gammas
      out[0] = sqrtf(fmaxf(total, 0.0f) / 83886080.0f);  // / (5 * 4096^2)
    }
  }
}

extern "C" void kernel_launch(void* const* d_in, const int* in_sizes, int n_in,
                              void* d_out, int out_size, void* d_ws, size_t ws_size,
                              hipStream_t stream) {
  const float* x1 = (const float*)d_in[0];
  const float* x2 = (const float*)d_in[1];
  unsigned short* Zb = (unsigned short*)d_ws;                       // 4 MiB bf16 Z
  float* norms = (float*)((char*)d_ws + (size_t)NT * D_DIM * 2);    // 32 KiB
  float* partials = norms + NT;                                     // 8.1 KiB
  unsigned int* counter = (unsigned int*)(partials + NBLK);
  float* out = (float*)d_out;

  mmd_prep<<<dim3(NT / 4), dim3(256), 0, stream>>>(x1, x2, Zb, norms, counter);
  mmd_main<<<dim3(NBLK), dim3(256), 0, stream>>>(Zb, norms, partials, counter, out);
}